// Round 4
// baseline (268.755 us; speedup 1.0000x reference)
//
#include <hip/hip_runtime.h>

// SparseMaxPool — R11 = R10 with the compile fix: __builtin_nontemporal_store
// requires a native vector type, not HIP's float4 class. Use
// ext_vector_type(4) for the emit path. Theory unchanged:
//
// R9 post-mortem: 8->10 waves/CU bought only 1.095x and no throughput pipe is
// near saturation (HBM-write 43%, LDS pipe ~17%, VALU ~11%) => latency-bound
// on the 31-stage shuffle chain: each __shfl is a ds_bpermute + s_waitcnt
// lgkmcnt(0) (full ~120cy LDS round-trip; the lgkm wait also drains the
// preceding scatter ds_write -> write completion coupled into the chain).
//
// R11 chain on DPP (pure VALU, zero lgkm):
//   k2s1 (29 stages): cur = max(cur, wave_shl:1(cur))      [ctrl 0x130]
//     (row_shr:N = lane i-N  =>  wave_shl:1 = lane i+1 = __shfl_down(cur,1);
//      bound_ctrl=0-fill, lane63 unused by masked writes)
//   k3s2 (m=15,23): t = max(c, shl1(c)); u = max(t, quad_perm[1,0,3,2](t))
//     => u[2l] = max(c[2l],c[2l+1],c[2l+2]); compact via one __shfl(u,2l).
// Chain LDS round-trips: 35 -> 2; per-stage dep ~120cy -> ~4-8cy.
// Masked-write garbage-safety proof unchanged (garbage front advances one
// lane/stage, never enters written lanes; DPP only alters garbage lanes).
// Emit: nontemporal stores (write-once data; avoid L2 pollution).
// Everything else = R9 (16 KB tile zeroed once, 4112 blocks x 4 tiles,
// prologue-loaded inputs, zero loads in steady state, 10 blocks/CU).

typedef float vfloat4 __attribute__((ext_vector_type(4)));

constexpr int S_LEN[31] = {
  63,62,61,60,59,58,57,56,55,54,53,52,51,50,49,
  24,23,22,21,20,19,18,17,
  8,7,6,5,4,3,2,1};
constexpr int S_ST[31] = {
  1,1,1,1,1,1,1,1,1,1,1,1,1,1,1,
  2,2,2,2,2,2,2,2,
  4,4,4,4,4,4,4,4};
constexpr int S_OFF[31] = {
  1,2,3,4,5,6,7,8,9,10,11,12,13,14,15,
  17,19,21,23,25,27,29,31,
  35,39,43,47,51,55,59,63};

// DPP move: CTRL=0x130 wave_shl:1 (lane i <- i+1), 0xB1 quad_perm [1,0,3,2]
// (lane i <- i^1). Full row/bank masks, bound_ctrl=0-fill.
template <int CTRL>
__device__ __forceinline__ float dpp_movf(float v) {
  return __int_as_float(
      __builtin_amdgcn_update_dpp(0, __float_as_int(v), CTRL, 0xF, 0xF, true));
}

__device__ __forceinline__ void process_tile(float* __restrict__ tile, int lane,
                                             float curx,
                                             float* __restrict__ optr) {
  // Diagonal (bank = lane%32, 2-way across the wave = free).
  tile[lane * 65] = curx;

  float cur = curx;
#pragma unroll
  for (int m = 0; m < 31; ++m) {
    if (m == 15 || m == 23) {             // k=3, s=2
      float t = fmaxf(cur, dpp_movf<0x130>(cur));  // t[l]=max(c[l],c[l+1])
      float u = fmaxf(t, dpp_movf<0xB1>(t));       // u[l]=max(t[l],t[l^1])
      cur = __shfl(u, 2 * lane);                   // cur[l]=u[2l]
    } else {                              // k=2, s=1 — pure-VALU DPP
      cur = fmaxf(cur, dpp_movf<0x130>(cur));
    }
    if (lane < S_LEN[m]) tile[lane * (S_ST[m] * 65) + S_OFF[m]] = cur;
  }

  // Emit: 16x (ds_read_b128 + nontemporal global_store_dwordx4), coalesced,
  // fixed LDS addresses. Per-wave DS ordering makes next tile's scatter safe.
  vfloat4* o4 = (vfloat4*)optr;
  const vfloat4* t4 = (const vfloat4*)tile;
#pragma unroll
  for (int it = 0; it < 16; ++it) {
    vfloat4 v = t4[it * 64 + lane];
    __builtin_nontemporal_store(v, &o4[it * 64 + lane]);
  }
}

__global__ void __launch_bounds__(64)
sparse_pool_kernel(const float* __restrict__ x, float* __restrict__ out,
                   int nrows, int ntiles) {
  __shared__ float tile[4096];            // 16 KB -> 10 blocks/CU
  const int lane = threadIdx.x;
  const int t0 = blockIdx.x;
  const int stride = gridDim.x;

  // Prologue: issue ALL input loads now (4 independent global loads).
  float xv0 = 1.0f, xv1 = 1.0f, xv2 = 1.0f, xv3 = 1.0f;
  if (t0 < nrows)                xv0 = x[(size_t)t0 * 64 + lane];
  if (t0 + stride < nrows)       xv1 = x[((size_t)t0 + stride) * 64 + lane];
  if (t0 + 2 * stride < nrows)   xv2 = x[((size_t)t0 + 2 * stride) * 64 + lane];
  if (t0 + 3 * stride < nrows)   xv3 = x[((size_t)t0 + 3 * stride) * 64 + lane];

  // Zero the tile ONCE (overlaps the loads). Valid positions are overwritten
  // every tile; the zero background persists (valid set is tile-invariant).
  const vfloat4 z = {0.f, 0.f, 0.f, 0.f};
#pragma unroll
  for (int i = 0; i < 16; ++i)
    ((vfloat4*)tile)[i * 64 + lane] = z;

  // Steady state: zero global loads -> no load-side vmcnt waits.
  if (t0 < ntiles)
    process_tile(tile, lane, xv0, out + (size_t)t0 * 4096);
  if (t0 + stride < ntiles)
    process_tile(tile, lane, xv1, out + ((size_t)t0 + stride) * 4096);
  if (t0 + 2 * stride < ntiles)
    process_tile(tile, lane, xv2, out + ((size_t)t0 + 2 * stride) * 4096);
  if (t0 + 3 * stride < ntiles)
    process_tile(tile, lane, xv3, out + ((size_t)t0 + 3 * stride) * 4096);
}

extern "C" void kernel_launch(void* const* d_in, const int* in_sizes, int n_in,
                              void* d_out, int out_size, void* d_ws, size_t ws_size,
                              hipStream_t stream) {
  const float* x = (const float*)d_in[0];        // fp32 input (32,512,64)
  float* out = (float*)d_out;                    // fp32 output

  const int nx     = in_sizes[0];                // B*D*64 = 1048576
  const int nrows  = nx / 64;                    // 16384 map tiles
  const int ntiles = out_size / 4096;            // 16448 = map + mask tiles

  // Exactly 4 tiles per block (4112 * 4 = 16448): uniform block duration,
  // prologue-loaded inputs, 10 blocks/CU resident (160 KB LDS exact fit).
  const int blocks = (ntiles + 3) / 4;
  sparse_pool_kernel<<<dim3(blocks), 64, 0, stream>>>(x, out, nrows, ntiles);
}

// Round 7
// 262.387 us; speedup vs baseline: 1.0243x; 1.0243x over previous
//
#include <hip/hip_runtime.h>

// SparseMaxPool — R14. R12/R13 hit "container failed twice" back-to-back
// (rounds before ran fine) — can't distinguish infra streak from the raw
// s_barrier+inline-asm pattern killing graph capture. R14 runs the SAME
// experiment (TLP 10 -> 32 waves/CU) with zero exotic constructs: plain
// __syncthreads() barriers. Its vmcnt(0) drain per tile is acceptable — the
// extra waves are precisely what hides store-retire latency.
//
// Theory (R11 post-mortem): chain latency exonerated (DPP chain had no
// effect). 247k cy kernel / 64.25 tiles/CU / 10 waves/CU => ~38k wave-cy per
// tile vs ~1k cy of issue => waves ~96% stalled; at 2.5 waves/SIMD the SIMDs
// usually have NO store-ready wave => VMEM-issue starvation. Fill at 6.5 TB/s
// on this buffer proves 2.5x store-path headroom.
//
// R14: 4-wave cooperative blocks (256 thr) share one 16 KB tile:
//  - all 4 waves run the pure-VALU DPP chain redundantly (~300 cy)
//  - scatter split by stage (wave w: m%4==w; wave3 adds diag -> 8/8/8/8)
//  - emit split by row-quarter: 4x (ds_read_b128 + store_dwordx4) per wave
//  - __launch_bounds__(256,8): 8 blocks/CU x 4 waves = 32 waves/CU (HW max),
//    3.2x R9's TLP. Grid 2048 blocks, grid-stride, <=1-tile imbalance.

typedef float vfloat4 __attribute__((ext_vector_type(4)));

constexpr int S_LEN[31] = {
  63,62,61,60,59,58,57,56,55,54,53,52,51,50,49,
  24,23,22,21,20,19,18,17,
  8,7,6,5,4,3,2,1};
constexpr int S_ST[31] = {
  1,1,1,1,1,1,1,1,1,1,1,1,1,1,1,
  2,2,2,2,2,2,2,2,
  4,4,4,4,4,4,4,4};
constexpr int S_OFF[31] = {
  1,2,3,4,5,6,7,8,9,10,11,12,13,14,15,
  17,19,21,23,25,27,29,31,
  35,39,43,47,51,55,59,63};

// DPP move: CTRL=0x130 wave_shl:1 (lane i <- i+1), 0xB1 quad_perm [1,0,3,2]
// (lane i <- i^1). Full row/bank masks, bound_ctrl=0-fill. Verified absmax
// 0.0 in R11.
template <int CTRL>
__device__ __forceinline__ float dpp_movf(float v) {
  return __int_as_float(
      __builtin_amdgcn_update_dpp(0, __float_as_int(v), CTRL, 0xF, 0xF, true));
}

__global__ void __launch_bounds__(256, 8)
sparse_pool_kernel(const float* __restrict__ x, float* __restrict__ out,
                   int nrows, int ntiles) {
  __shared__ float tile[4096];            // 16 KB, shared by 4 waves
  const int tid  = threadIdx.x;
  const int lane = tid & 63;
  const int w    = tid >> 6;

  // Zero the tile ONCE (256 threads x 4 float4). Valid positions are
  // overwritten every tile; zero background persists (valid set invariant).
  const vfloat4 z = {0.f, 0.f, 0.f, 0.f};
#pragma unroll
  for (int i = 0; i < 4; ++i)
    ((vfloat4*)tile)[i * 256 + tid] = z;
  __syncthreads();

  const int stride = gridDim.x;
  int t = blockIdx.x;
  float curx = 0.f;
  if (t < ntiles) curx = (t < nrows) ? x[(size_t)t * 64 + lane] : 1.0f;

  for (; t < ntiles; t += stride) {
    // Diagonal by wave 3 (it has only 7 scatter stages -> balanced 8/8/8/8).
    if (w == 3) tile[lane * 65] = curx;

    // Full DPP chain in every wave (pure VALU); each wave scatters only its
    // own stages. Masked-write garbage-safety proof unchanged from R7-R11.
    float cur = curx;
#pragma unroll
    for (int m = 0; m < 31; ++m) {
      if (m == 15 || m == 23) {           // k=3, s=2
        float a = fmaxf(cur, dpp_movf<0x130>(cur));  // a[l]=max(c[l],c[l+1])
        float u = fmaxf(a, dpp_movf<0xB1>(a));       // u[l]=max(a[l],a[l^1])
        cur = __shfl(u, 2 * lane);                   // cur[l]=u[2l]
      } else {                            // k=2, s=1 — pure-VALU DPP
        cur = fmaxf(cur, dpp_movf<0x130>(cur));
      }
      if ((m & 3) == w && lane < S_LEN[m])
        tile[lane * (S_ST[m] * 65) + S_OFF[m]] = cur;
    }

    // Prefetch next tile's input; overlaps the barrier/emit below.
    const int tn = t + stride;
    float nx = 0.f;
    if (tn < ntiles) nx = (tn < nrows) ? x[(size_t)tn * 64 + lane] : 1.0f;

    __syncthreads();                      // scatter visible to all waves

    // Emit quarter: rows [4w, 4w+4) — 4x (ds_read_b128 + store_dwordx4).
    vfloat4* o4 = (vfloat4*)(out + (size_t)t * 4096);
    const vfloat4* t4 = (const vfloat4*)tile;
#pragma unroll
    for (int it = 0; it < 4; ++it) {
      const int row = w * 4 + it;
      o4[row * 64 + lane] = t4[row * 64 + lane];
    }

    __syncthreads();                      // emit reads done before next scatter

    curx = nx;
  }
}

extern "C" void kernel_launch(void* const* d_in, const int* in_sizes, int n_in,
                              void* d_out, int out_size, void* d_ws, size_t ws_size,
                              hipStream_t stream) {
  const float* x = (const float*)d_in[0];        // fp32 input (32,512,64)
  float* out = (float*)d_out;                    // fp32 output

  const int nx     = in_sizes[0];                // B*D*64 = 1048576
  const int nrows  = nx / 64;                    // 16384 map tiles
  const int ntiles = out_size / 4096;            // 16448 = map + mask tiles

  // 2048 blocks x 4 waves: 8 blocks/CU (16 KB LDS, <=64 VGPR) = 32 waves/CU.
  // Grid-stride: 64 blocks do 9 tiles, rest 8 (<=1-tile tail imbalance).
  int blocks = (ntiles + 7) / 8;
  if (blocks > 2048) blocks = 2048;
  sparse_pool_kernel<<<dim3(blocks), 256, 0, stream>>>(x, out, nrows, ntiles);
}